// Round 5
// baseline (228.192 us; speedup 1.0000x reference)
//
#include <hip/hip_runtime.h>
#include <stdint.h>

// LinearAttention: x[2,8192,1024] -> qkv proj -> per-head softmaxes ->
// context = softmax_n(k)^T v -> out = softmax_d(q) @ ctx -> @ W_out + b.
// Heavy GEMMs: 256x256 f16 MFMA, 4-slot pipelined K-loop:
// each slot issues NEXT phase's ds_reads (lookahead) + one stage_half, then
// runs current MFMA burst -> LDS-read drain overlaps matrix pipe (R4 showed
// read/MFMA convoy: 5500 cyc/K-tile vs 2060 MFMA floor).
//
// Slot schedule per tile t2 (one barrier per slot):
//  slot0: read b23(t2);           STG A0(t2+1)->other; MFMA(0,0) a0*b01; BAR
//  slot1: read a1(t2);            STG A1(t2+1)->other; MFMA(0,1) a0*b23; BAR
//  slot2:                         STG B0(t2+2)->cur; vmcnt(2);
//                                 MFMA(1,0) a1*b01; BAR
//  slot3: read a0,b01(t2+1)<-other; STG B1(t2+2)->cur; MFMA(1,1) a1*b23; BAR
// vmcnt(2)@slot2: outstanding = B1(t2+1),A0(t2+1),A1(t2+1)[6] + B0(t2+2)[2];
// wait <=2 => tile t2+1's A + B0 resident; barrier makes it block-wide before
// slot3's other-buffer reads. Region liveness verified: B last read slot0,
// overwritten slot2/3; A last read slot1, overwritten slot0(t2+1).

typedef _Float16 half4 __attribute__((ext_vector_type(4)));
typedef _Float16 half8 __attribute__((ext_vector_type(8)));
typedef float f32x4 __attribute__((ext_vector_type(4)));

// ---- workspace byte offsets (total ~113.6 MB) ----
#define WS_XB 0UL             // x as f16          [16384][1024]   33.55MB
#define WS_WQKVT 33554432UL   // W_qkv^T f16       [1536][1024]     3.15MB
#define WS_WOUTT 36700160UL   // W_out^T f16       [1024][512]      1.05MB
#define WS_QH 37748736UL      // q logits f16      [16][8192][64]  16.78MB
#define WS_KH 54525952UL      // k logits f16      [16][8192][64]  16.78MB
#define WS_VH 71303168UL      // v f16             [16][8192][64]  16.78MB
#define WS_ATTN 88080384UL    // attn out f16      [16384][512]    16.78MB
#define WS_CTXPART 104857600UL// ctx partials f32  [512][4096]      8.39MB
#define WS_COLPART 113246208UL// colsum partials   [512][64]        0.13MB
#define WS_CTX 113377280UL    // ctx f32           [16][64][64]     0.26MB

__device__ __forceinline__ void gld16(const void* g, void* l) {
  // async global->LDS, 16B per lane; LDS dest = wave-uniform base + lane*16
  __builtin_amdgcn_global_load_lds(
      (const __attribute__((address_space(1))) unsigned int*)g,
      (__attribute__((address_space(3))) unsigned int*)l, 16, 0, 0);
}

// Fused prep: cvt x (f32->f16), transpose+cvt W_qkv, transpose+cvt W_out.
__global__ void prep_kernel(const float* __restrict__ x,
                            const float* __restrict__ Wqkv,
                            const float* __restrict__ Wout,
                            _Float16* __restrict__ xb,
                            _Float16* __restrict__ wqkvT,
                            _Float16* __restrict__ woutT) {
  const int blk = blockIdx.x;
  if (blk < 16384) {
    int i = blk * 256 + threadIdx.x;  // 4 f32 per thread
    f32x4 v = *(const f32x4*)(x + (size_t)i * 4);
    half4 h = {(_Float16)v[0], (_Float16)v[1], (_Float16)v[2], (_Float16)v[3]};
    *(half4*)(xb + (size_t)i * 4) = h;
  } else if (blk < 16384 + 6144) {
    int i = (blk - 16384) * 256 + threadIdx.x;  // [0, 1536*1024)
    int c = i >> 10, r = i & 1023;
    wqkvT[i] = (_Float16)Wqkv[(size_t)r * 1536 + c];
  } else {
    int i = (blk - 16384 - 6144) * 256 + threadIdx.x;  // [0, 1024*512)
    int c = i >> 9, r = i & 511;
    woutT[i] = (_Float16)Wout[(size_t)r * 1024 + c];
  }
}

// ---------------- 256x256 pipelined GEMM ----------------
// A[M][K] f16 row-major, BT[N][K] f16 row-major. 512 threads = 8 waves (2Mx4N),
// per-wave output 128x64. BK=64, LDS = 2 dbuf x (A 32KB + B 32KB) = 128KB.
// LDS tile layout: [256 rows][128 B] with XOR swizzle addr ^= ((row&7)<<4);
// staged linearly via global_load_lds with inverse-swizzled global source.

// stage one half-tile (128 rows x 64 f16) = 2 x global_load_lds(16B)/thread
__device__ __forceinline__ void stage_half(const _Float16* __restrict__ G, int K,
                                           int rowbase, int kt, char* ldsHalf,
                                           int t) {
  const int srow = t >> 3;
  const int scol = ((t & 7) ^ ((t >> 3) & 7)) * 8;  // inverse-swizzled col (f16)
  const int w = t >> 6;
  gld16(G + (size_t)(rowbase + srow) * K + kt + scol, ldsHalf + w * 1024);
  gld16(G + (size_t)(rowbase + 64 + srow) * K + kt + scol,
        ldsHalf + 8192 + w * 1024);
}

// 16 MFMA quadrant: acc rows MH*4.., cols NH*2..; A-frags from array `aarr`
#define MFMA_Q(aarr, MH, NH)                                                   \
  do {                                                                         \
    __builtin_amdgcn_s_setprio(1);                                             \
    _Pragma("unroll") for (int i_ = 0; i_ < 4; ++i_)                           \
        _Pragma("unroll") for (int j_ = 0; j_ < 2; ++j_)                       \
            _Pragma("unroll") for (int kk_ = 0; kk_ < 2; ++kk_)                \
                acc[(MH) * 4 + i_][(NH) * 2 + j_] =                            \
        __builtin_amdgcn_mfma_f32_16x16x32_f16(                                \
            aarr[i_][kk_], b[(NH) * 2 + j_][kk_],                              \
            acc[(MH) * 4 + i_][(NH) * 2 + j_], 0, 0, 0);                       \
    __builtin_amdgcn_s_setprio(0);                                             \
  } while (0)

// read A-half MH rows [wm*128 + MH*64, +63] into array dst
#define LDA_INTO(dst, src, MH)                                                 \
  do {                                                                         \
    _Pragma("unroll") for (int i_ = 0; i_ < 4; ++i_)                           \
        _Pragma("unroll") for (int kk_ = 0; kk_ < 2; ++kk_) {                  \
      int off_ = (wm * 128 + ((MH) * 4 + i_) * 16 + fr) * 128 + kk_ * 64 +     \
                 qq * 16;                                                      \
      dst[i_][kk_] = *(const half8*)((src) + (off_ ^ swzx));                   \
    }                                                                          \
  } while (0)

// read B quarter NH rows [wn*64 + NH*32, +31] into b[NH*2 .. NH*2+1]
#define LDB_INTO(src, NH)                                                      \
  do {                                                                         \
    _Pragma("unroll") for (int j_ = 0; j_ < 2; ++j_)                           \
        _Pragma("unroll") for (int kk_ = 0; kk_ < 2; ++kk_) {                  \
      int ni_ = (NH) * 2 + j_;                                                 \
      int off_ = (wn * 64 + ni_ * 16 + fr) * 128 + kk_ * 64 + qq * 16;         \
      b[ni_][kk_] = *(const half8*)((src) + (off_ ^ swzx));                    \
    }                                                                          \
  } while (0)

#define BAR() __builtin_amdgcn_s_barrier()

// EPI 0: scatter qkv -> per-head q/k/v f16. EPI 1: +bias, f32 out ldc=1024.
template <int EPI>
__global__ __launch_bounds__(512, 2) void gemm8p(
    const _Float16* __restrict__ A, const _Float16* __restrict__ BT, int K,
    int NTN, _Float16* __restrict__ oQ, _Float16* __restrict__ oK,
    _Float16* __restrict__ oV, float* __restrict__ oC,
    const float* __restrict__ bias) {
  __shared__ char lds[131072];
  const int t = threadIdx.x;
  const int l = t & 63, w = t >> 6;
  const int wm = w >> 2, wn = w & 3;  // wave -> (M half, N quarter)
  const int fr = l & 15, qq = l >> 4;
  const int swzx = (fr & 7) << 4;

  // T1: bijective XCD chunking (nwg % 8 == 0), tileM-major within chunk
  const int nwg = gridDim.x;
  const int cpx = nwg >> 3;
  const int wg = (blockIdx.x & 7) * cpx + (blockIdx.x >> 3);
  const int tileM = wg / NTN, tileN = wg - tileM * NTN;
  const int mbase = tileM * 256, nbase = tileN * 256;

  const int NT = K >> 6;
  f32x4 acc[8][4] = {};
  half8 a0[4][2], a1[4][2], b[4][2];

  // stage half x of K-tile `tile`: x 0=A0, 3=A1, 1=B0, 2=B1
  auto STG = [&](int tile, int x) {
    int kt = tile * 64;
    if (kt > K - 64) kt = K - 64;  // tail clamp: keep issue counts identical
    char* base = lds + ((tile & 1) << 16);
    if (x == 0)
      stage_half(A, K, mbase, kt, base, t);
    else if (x == 1)
      stage_half(BT, K, nbase, kt, base + 32768, t);
    else if (x == 2)
      stage_half(BT, K, nbase + 128, kt, base + 32768 + 16384, t);
    else
      stage_half(A, K, mbase + 128, kt, base + 16384, t);
  };

  // prologue: tile0 fully + B0(1); vmcnt(2) -> tile0 resident; then preload
  // a0(0), b01(0) frags and stage B1(1) ("slot3 of t2=-1").
  STG(0, 0); STG(0, 3); STG(0, 1); STG(0, 2);
  STG(1, 1);
  asm volatile("s_waitcnt vmcnt(2)" ::: "memory");
  BAR();
  {
    const char* ldsA0 = lds;
    const char* ldsB0 = lds + 32768;
    LDA_INTO(a0, ldsA0, 0);
    LDB_INTO(ldsB0, 0);
  }
  STG(1, 2);
  BAR();

  for (int t2 = 0; t2 < NT; ++t2) {
    const char* ldsA = lds + ((t2 & 1) << 16);
    const char* ldsB = ldsA + 32768;
    const char* ldsAn = lds + (((t2 + 1) & 1) << 16);
    const char* ldsBn = ldsAn + 32768;
    // slot0: lookahead b23(t2); stage A0(t2+1)->other; MFMA(0,0)=a0*b01
    LDB_INTO(ldsB, 1);
    STG(t2 + 1, 0);
    MFMA_Q(a0, 0, 0);
    BAR();
    // slot1: lookahead a1(t2); stage A1(t2+1)->other; MFMA(0,1)=a0*b23
    LDA_INTO(a1, ldsA, 1);
    STG(t2 + 1, 3);
    MFMA_Q(a0, 0, 1);
    BAR();
    // slot2: stage B0(t2+2)->cur; vmcnt(2): tile t2+1 A+B0 resident;
    // MFMA(1,0)=a1*b01
    STG(t2 + 2, 1);
    asm volatile("s_waitcnt vmcnt(2)" ::: "memory");
    MFMA_Q(a1, 1, 0);
    BAR();
    // slot3: lookahead a0,b01(t2+1) from other buf; stage B1(t2+2)->cur;
    // MFMA(1,1)=a1*b23
    LDA_INTO(a0, ldsAn, 0);
    LDB_INTO(ldsBn, 0);
    STG(t2 + 2, 2);
    MFMA_Q(a1, 1, 1);
    BAR();
  }
  asm volatile("s_waitcnt vmcnt(0)" ::: "memory");  // drain tail stages

  // C/D layout: col = lane&15 (=fr), row = (lane>>4)*4 + reg (=qq*4+r)
  if (EPI == 0) {
#pragma unroll
    for (int mi = 0; mi < 8; ++mi) {
      const int grow = mbase + wm * 128 + mi * 16 + qq * 4;
      const int bidx = grow >> 13, n = grow & 8191;
#pragma unroll
      for (int ni = 0; ni < 4; ++ni) {
        const int gcol = nbase + wn * 64 + ni * 16 + fr;
        const int which = gcol >> 9, h = (gcol >> 6) & 7, d = gcol & 63;
        _Float16* dst = (which == 0) ? oQ : ((which == 1) ? oK : oV);
        const size_t base = ((size_t)((bidx << 3) + h) * 8192 + n) * 64 + d;
#pragma unroll
        for (int r = 0; r < 4; ++r)
          dst[base + (size_t)r * 64] = (_Float16)acc[mi][ni][r];
      }
    }
  } else {
#pragma unroll
    for (int mi = 0; mi < 8; ++mi) {
      const int grow = mbase + wm * 128 + mi * 16 + qq * 4;
#pragma unroll
      for (int ni = 0; ni < 4; ++ni) {
        const int gcol = nbase + wn * 64 + ni * 16 + fr;
        const float bb = bias[gcol];
#pragma unroll
        for (int r = 0; r < 4; ++r)
          oC[(size_t)(grow + r) * 1024 + gcol] = acc[mi][ni][r] + bb;
      }
    }
  }
}

// Per (bh, 256-row chunk): stage exp(k) and v (f16->f32) in LDS, accumulate
// 64x64 partial ctx + per-column partial sums. No atomics -> deterministic.
__global__ __launch_bounds__(256) void ctx_partial_kernel(
    const _Float16* __restrict__ kh, const _Float16* __restrict__ vh,
    float* __restrict__ ctxpart, float* __restrict__ colpart) {
  __shared__ float se[128 * 64];
  __shared__ float sv[128 * 64];
  const int t = threadIdx.x;
  const int bh = blockIdx.x >> 5, ch = blockIdx.x & 31;
  const size_t rowbase = ((size_t)bh * 8192 + ch * 256) * 64;
  const int d0 = (t & 15) * 4, e0 = (t >> 4) * 4;
  float acc[4][4] = {};
  float colacc = 0.f;
  for (int sub = 0; sub < 2; ++sub) {
    const _Float16* kp = kh + rowbase + (size_t)sub * (128 * 64);
    const _Float16* vp = vh + rowbase + (size_t)sub * (128 * 64);
    __syncthreads();
    for (int i = t; i < 2048; i += 256) {
      half4 a = ((const half4*)kp)[i];
      half4 b = ((const half4*)vp)[i];
      f32x4 fa = {__expf((float)a[0]), __expf((float)a[1]),
                  __expf((float)a[2]), __expf((float)a[3])};
      f32x4 fb = {(float)b[0], (float)b[1], (float)b[2], (float)b[3]};
      *(f32x4*)&se[i * 4] = fa;
      *(f32x4*)&sv[i * 4] = fb;
    }
    __syncthreads();
    if (t < 64) {
      for (int n = 0; n < 128; ++n) colacc += se[n * 64 + t];
    }
    for (int n = 0; n < 128; ++n) {
      f32x4 a = *(const f32x4*)&se[n * 64 + d0];
      f32x4 b = *(const f32x4*)&sv[n * 64 + e0];
#pragma unroll
      for (int i2 = 0; i2 < 4; ++i2)
#pragma unroll
        for (int j = 0; j < 4; ++j) acc[i2][j] += a[i2] * b[j];
    }
  }
  float* cp = ctxpart + (size_t)blockIdx.x * 4096;
#pragma unroll
  for (int i2 = 0; i2 < 4; ++i2)
#pragma unroll
    for (int j = 0; j < 4; ++j) cp[(d0 + i2) * 64 + e0 + j] = acc[i2][j];
  if (t < 64) colpart[blockIdx.x * 64 + t] = colacc;
}

// ctx[bh][d][e] = (sum_c ctxpart) / (sum_c colpart[d])
__global__ void ctx_reduce_kernel(const float* __restrict__ ctxpart,
                                  const float* __restrict__ colpart,
                                  float* __restrict__ ctx) {
  int i = blockIdx.x * 256 + threadIdx.x;  // 65536 total
  int bh = i >> 12, r = i & 4095, d = r >> 6;
  float s = 0.f, v = 0.f;
  for (int c = 0; c < 32; ++c) {
    s += colpart[((size_t)bh * 32 + c) * 64 + d];
    v += ctxpart[((size_t)bh * 32 + c) * 4096 + r];
  }
  ctx[i] = v / s;
}

// Per (bh, 128-row chunk): stage q logits, softmax rows in LDS (wave=row),
// then out[n][e] = sum_d softq[n][d]*ctx[d][e]; write attn f16 [16384][512].
__global__ __launch_bounds__(256) void qctx_kernel(const _Float16* __restrict__ qh,
                                                   const float* __restrict__ ctx,
                                                   _Float16* __restrict__ attn) {
  __shared__ float sq[128 * 64];
  __shared__ float sc[64 * 64];
  const int t = threadIdx.x;
  const int bh = blockIdx.x >> 6, ch = blockIdx.x & 63;
  const int b = bh >> 3, h = bh & 7;
  const _Float16* qb = qh + ((size_t)bh * 8192 + ch * 128) * 64;
  for (int i = t; i < 2048; i += 256) {
    half4 a = ((const half4*)qb)[i];
    f32x4 f = {(float)a[0], (float)a[1], (float)a[2], (float)a[3]};
    *(f32x4*)&sq[i * 4] = f;
  }
  const float* cb = ctx + (size_t)bh * 4096;
  for (int i = t; i < 1024; i += 256)
    *(f32x4*)&sc[i * 4] = *(const f32x4*)&cb[i * 4];
  __syncthreads();
  const int w = t >> 6, l = t & 63;
  for (int r = w * 32; r < w * 32 + 32; ++r) {
    float e = __expf(sq[r * 64 + l]);
    float s = e;
#pragma unroll
    for (int off = 1; off < 64; off <<= 1) s += __shfl_xor(s, off, 64);
    sq[r * 64 + l] = e / s;
  }
  __syncthreads();
  // d-blocked, vectorized: 4 c-rows + 8 q-f32x4 reads per d0 step
  const int e0 = (t & 15) * 4, n0 = (t >> 4) * 8;
  float acc[8][4] = {};
  for (int d04 = 0; d04 < 16; ++d04) {
    const int d0 = d04 * 4;
    f32x4 c4[4];
#pragma unroll
    for (int dd = 0; dd < 4; ++dd) c4[dd] = *(const f32x4*)&sc[(d0 + dd) * 64 + e0];
#pragma unroll
    for (int i = 0; i < 8; ++i) {
      f32x4 qv = *(const f32x4*)&sq[(n0 + i) * 64 + d0];
#pragma unroll
      for (int dd = 0; dd < 4; ++dd)
#pragma unroll
        for (int j = 0; j < 4; ++j) acc[i][j] += qv[dd] * c4[dd][j];
    }
  }
#pragma unroll
  for (int i = 0; i < 8; ++i) {
    int n = ch * 128 + n0 + i;
    half4 o = {(_Float16)acc[i][0], (_Float16)acc[i][1], (_Float16)acc[i][2],
               (_Float16)acc[i][3]};
    *(half4*)&attn[(size_t)(b * 8192 + n) * 512 + h * 64 + e0] = o;
  }
}

extern "C" void kernel_launch(void* const* d_in, const int* in_sizes, int n_in,
                              void* d_out, int out_size, void* d_ws, size_t ws_size,
                              hipStream_t stream) {
  const float* x = (const float*)d_in[0];
  const float* Wqkv = (const float*)d_in[1];
  const float* Wout = (const float*)d_in[2];
  const float* bout = (const float*)d_in[3];
  float* out = (float*)d_out;
  char* ws = (char*)d_ws;

  _Float16* xb = (_Float16*)(ws + WS_XB);
  _Float16* wqkvT = (_Float16*)(ws + WS_WQKVT);
  _Float16* woutT = (_Float16*)(ws + WS_WOUTT);
  _Float16* qh = (_Float16*)(ws + WS_QH);
  _Float16* kh = (_Float16*)(ws + WS_KH);
  _Float16* vh = (_Float16*)(ws + WS_VH);
  _Float16* attn = (_Float16*)(ws + WS_ATTN);
  float* ctxpart = (float*)(ws + WS_CTXPART);
  float* colpart = (float*)(ws + WS_COLPART);
  float* ctx = (float*)(ws + WS_CTX);

  // 1) fused converts (x cvt + both weight transposes)
  prep_kernel<<<24576, 256, 0, stream>>>(x, Wqkv, Wout, xb, wqkvT, woutT);
  // 2) qkv projection (M=16384,N=1536,K=1024), scattered to per-head q/k/v
  gemm8p<0><<<384, 512, 0, stream>>>(xb, wqkvT, 1024, 6, qh, kh, vh, nullptr,
                                     nullptr);
  // 3) context = exp(k)^T v partials + colsums, then deterministic reduce
  ctx_partial_kernel<<<512, 256, 0, stream>>>(kh, vh, ctxpart, colpart);
  ctx_reduce_kernel<<<256, 256, 0, stream>>>(ctxpart, colpart, ctx);
  // 4) softmax(q) @ ctx -> attn
  qctx_kernel<<<1024, 256, 0, stream>>>(qh, ctx, attn);
  // 5) output projection + bias (M=16384,N=1024,K=512)
  gemm8p<1><<<256, 512, 0, stream>>>(attn, woutT, 512, 4, nullptr, nullptr,
                                     nullptr, out, bout);
}

// Round 6
// 193.849 us; speedup vs baseline: 1.1772x; 1.1772x over previous
//
#include <hip/hip_runtime.h>
#include <stdint.h>

// LinearAttention: x[2,8192,1024] -> qkv proj -> per-head softmaxes ->
// context = softmax_n(k)^T v -> out = softmax_d(q) @ ctx -> @ W_out + b.
// GEMMs: 256x256 8-phase f16 MFMA template (reverted to R4-measured version;
// R5's lookahead schedule regressed 1.6x via shallow-vmcnt HBM-latency
// exposure). ctx_partial: global-direct 8x8 register outer product.
//
// GEMM stage schedule: per iter t2,
//   ph0: stage A0(t2+1) -> other buf   (A halves live until ph2)
//   ph1: stage A1(t2+1) -> other buf
//   ph2: stage B0(t2+2) -> current buf (B last read at ph1)
//   ph3: stage B1(t2+2) -> current buf; s_waitcnt vmcnt(4) -> tile t2+1 ready

typedef _Float16 half4 __attribute__((ext_vector_type(4)));
typedef _Float16 half8 __attribute__((ext_vector_type(8)));
typedef float f32x4 __attribute__((ext_vector_type(4)));

// ---- workspace byte offsets (total ~113.6 MB) ----
#define WS_XB 0UL             // x as f16          [16384][1024]   33.55MB
#define WS_WQKVT 33554432UL   // W_qkv^T f16       [1536][1024]     3.15MB
#define WS_WOUTT 36700160UL   // W_out^T f16       [1024][512]      1.05MB
#define WS_QH 37748736UL      // q logits f16      [16][8192][64]  16.78MB
#define WS_KH 54525952UL      // k logits f16      [16][8192][64]  16.78MB
#define WS_VH 71303168UL      // v f16             [16][8192][64]  16.78MB
#define WS_ATTN 88080384UL    // attn out f16      [16384][512]    16.78MB
#define WS_CTXPART 104857600UL// ctx partials f32  [512][4096]      8.39MB
#define WS_COLPART 113246208UL// colsum partials   [512][64]        0.13MB
#define WS_CTX 113377280UL    // ctx f32           [16][64][64]     0.26MB

__device__ __forceinline__ void gld16(const void* g, void* l) {
  // async global->LDS, 16B per lane; LDS dest = wave-uniform base + lane*16
  __builtin_amdgcn_global_load_lds(
      (const __attribute__((address_space(1))) unsigned int*)g,
      (__attribute__((address_space(3))) unsigned int*)l, 16, 0, 0);
}

// Fused prep: cvt x (f32->f16), transpose+cvt W_qkv, transpose+cvt W_out.
__global__ void prep_kernel(const float* __restrict__ x,
                            const float* __restrict__ Wqkv,
                            const float* __restrict__ Wout,
                            _Float16* __restrict__ xb,
                            _Float16* __restrict__ wqkvT,
                            _Float16* __restrict__ woutT) {
  const int blk = blockIdx.x;
  if (blk < 16384) {
    int i = blk * 256 + threadIdx.x;  // 4 f32 per thread
    f32x4 v = *(const f32x4*)(x + (size_t)i * 4);
    half4 h = {(_Float16)v[0], (_Float16)v[1], (_Float16)v[2], (_Float16)v[3]};
    *(half4*)(xb + (size_t)i * 4) = h;
  } else if (blk < 16384 + 6144) {
    int i = (blk - 16384) * 256 + threadIdx.x;  // [0, 1536*1024)
    int c = i >> 10, r = i & 1023;
    wqkvT[i] = (_Float16)Wqkv[(size_t)r * 1536 + c];
  } else {
    int i = (blk - 16384 - 6144) * 256 + threadIdx.x;  // [0, 1024*512)
    int c = i >> 9, r = i & 511;
    woutT[i] = (_Float16)Wout[(size_t)r * 1024 + c];
  }
}

// ---------------- 256x256 8-phase GEMM (R4-measured) ----------------
// A[M][K] f16 row-major, BT[N][K] f16 row-major. 512 threads = 8 waves (2Mx4N),
// per-wave output 128x64. BK=64, LDS = 2 dbuf x (A 32KB + B 32KB) = 128KB.
// LDS tile layout: [256 rows][128 B] with XOR swizzle addr ^= ((row&7)<<4);
// staged linearly via global_load_lds with inverse-swizzled global source.

// stage one half-tile (128 rows x 64 f16) = 2 x global_load_lds(16B)/thread
__device__ __forceinline__ void stage_half(const _Float16* __restrict__ G, int K,
                                           int rowbase, int kt, char* ldsHalf,
                                           int t) {
  const int srow = t >> 3;
  const int scol = ((t & 7) ^ ((t >> 3) & 7)) * 8;  // inverse-swizzled col (f16)
  const int w = t >> 6;
  gld16(G + (size_t)(rowbase + srow) * K + kt + scol, ldsHalf + w * 1024);
  gld16(G + (size_t)(rowbase + 64 + srow) * K + kt + scol,
        ldsHalf + 8192 + w * 1024);
}

// Frag loads are compiler-visible; scoreboard emits counted lgkmcnt waits so
// MFMA issue overlaps the ds_read drain.
#define PHASE_MFMA(MH, NH)                                                     \
  do {                                                                         \
    __builtin_amdgcn_s_barrier();                                              \
    __builtin_amdgcn_s_setprio(1);                                             \
    _Pragma("unroll") for (int i_ = 0; i_ < 4; ++i_)                           \
        _Pragma("unroll") for (int j_ = 0; j_ < 2; ++j_)                       \
            _Pragma("unroll") for (int kk_ = 0; kk_ < 2; ++kk_)                \
                acc[(MH) * 4 + i_][(NH) * 2 + j_] =                            \
        __builtin_amdgcn_mfma_f32_16x16x32_f16(                                \
            a[i_][kk_], b[(NH) * 2 + j_][kk_],                                 \
            acc[(MH) * 4 + i_][(NH) * 2 + j_], 0, 0, 0);                       \
    __builtin_amdgcn_s_setprio(0);                                             \
  } while (0)

#define LDA_HALF(MH)                                                           \
  do {                                                                         \
    _Pragma("unroll") for (int i_ = 0; i_ < 4; ++i_)                           \
        _Pragma("unroll") for (int kk_ = 0; kk_ < 2; ++kk_) {                  \
      int off_ = (wm * 128 + ((MH) * 4 + i_) * 16 + fr) * 128 + kk_ * 64 +     \
                 qq * 16;                                                      \
      a[i_][kk_] = *(const half8*)(ldsA + (off_ ^ swzx));                      \
    }                                                                          \
  } while (0)

#define LDB_HALF(NH)                                                           \
  do {                                                                         \
    _Pragma("unroll") for (int j_ = 0; j_ < 2; ++j_)                           \
        _Pragma("unroll") for (int kk_ = 0; kk_ < 2; ++kk_) {                  \
      int ni_ = (NH) * 2 + j_;                                                 \
      int off_ = (wn * 64 + ni_ * 16 + fr) * 128 + kk_ * 64 + qq * 16;         \
      b[ni_][kk_] = *(const half8*)(ldsB + (off_ ^ swzx));                     \
    }                                                                          \
  } while (0)

// EPI 0: scatter qkv -> per-head q/k/v f16. EPI 1: +bias, f32 out ldc=1024.
template <int EPI>
__global__ __launch_bounds__(512, 2) void gemm8p(
    const _Float16* __restrict__ A, const _Float16* __restrict__ BT, int K,
    int NTN, _Float16* __restrict__ oQ, _Float16* __restrict__ oK,
    _Float16* __restrict__ oV, float* __restrict__ oC,
    const float* __restrict__ bias) {
  __shared__ char lds[131072];
  const int t = threadIdx.x;
  const int l = t & 63, w = t >> 6;
  const int wm = w >> 2, wn = w & 3;  // wave -> (M half, N quarter)
  const int fr = l & 15, qq = l >> 4;
  const int swzx = (fr & 7) << 4;

  // T1: bijective XCD chunking (nwg % 8 == 0), tileM-major within chunk
  const int nwg = gridDim.x;
  const int cpx = nwg >> 3;
  const int wg = (blockIdx.x & 7) * cpx + (blockIdx.x >> 3);
  const int tileM = wg / NTN, tileN = wg - tileM * NTN;
  const int mbase = tileM * 256, nbase = tileN * 256;

  const int NT = K >> 6;
  f32x4 acc[8][4] = {};
  half8 a[4][2], b[4][2];

  // stage half x of K-tile `tile`: x 0=A0, 3=A1, 1=B0, 2=B1
  auto STG = [&](int tile, int x) {
    int kt = tile * 64;
    if (kt > K - 64) kt = K - 64;  // tail clamp: keep issue counts identical
    char* base = lds + ((tile & 1) << 16);
    if (x == 0)
      stage_half(A, K, mbase, kt, base, t);
    else if (x == 1)
      stage_half(BT, K, nbase, kt, base + 32768, t);
    else if (x == 2)
      stage_half(BT, K, nbase + 128, kt, base + 32768 + 16384, t);
    else
      stage_half(A, K, mbase + 128, kt, base + 16384, t);
  };

  // prologue: all of tile0 (8 loads/thread) + B0,B1 of tile1 (4 loads/thread)
  STG(0, 0); STG(0, 3); STG(0, 1); STG(0, 2);
  STG(1, 1); STG(1, 2);
  asm volatile("s_waitcnt vmcnt(4)" ::: "memory");  // tile0 resident
  __builtin_amdgcn_s_barrier();

  for (int t2 = 0; t2 < NT; ++t2) {
    const char* ldsA = lds + ((t2 & 1) << 16);
    const char* ldsB = ldsA + 32768;
    // ph0: A rows [wm*128, +63], B rows [wn*64, +31]; stage A0(t2+1)->other buf
    LDA_HALF(0);
    LDB_HALF(0);
    STG(t2 + 1, 0);
    PHASE_MFMA(0, 0);
    __builtin_amdgcn_s_barrier();
    // ph1: B rows [wn*64+32, +31]; stage A1(t2+1)->other buf
    LDB_HALF(1);
    STG(t2 + 1, 3);
    PHASE_MFMA(0, 1);
    __builtin_amdgcn_s_barrier();
    // ph2: A rows [wm*128+64, +63]; B fully consumed -> stage B0(t2+2)->cur buf
    LDA_HALF(1);
    STG(t2 + 2, 1);
    PHASE_MFMA(1, 0);
    __builtin_amdgcn_s_barrier();
    // ph3: no frag loads; stage B1(t2+2)->cur buf; counted wait: tile t2+1
    // resident (only B(t2+2)'s 4 loads may remain in flight)
    STG(t2 + 2, 2);
    PHASE_MFMA(1, 1);
    asm volatile("s_waitcnt vmcnt(4)" ::: "memory");
    __builtin_amdgcn_s_barrier();
  }
  asm volatile("s_waitcnt vmcnt(0)" ::: "memory");  // drain tail stages

  // C/D layout: col = lane&15 (=fr), row = (lane>>4)*4 + reg (=qq*4+r)
  if (EPI == 0) {
#pragma unroll
    for (int mi = 0; mi < 8; ++mi) {
      const int grow = mbase + wm * 128 + mi * 16 + qq * 4;
      const int bidx = grow >> 13, n = grow & 8191;
#pragma unroll
      for (int ni = 0; ni < 4; ++ni) {
        const int gcol = nbase + wn * 64 + ni * 16 + fr;
        const int which = gcol >> 9, h = (gcol >> 6) & 7, d = gcol & 63;
        _Float16* dst = (which == 0) ? oQ : ((which == 1) ? oK : oV);
        const size_t base = ((size_t)((bidx << 3) + h) * 8192 + n) * 64 + d;
#pragma unroll
        for (int r = 0; r < 4; ++r)
          dst[base + (size_t)r * 64] = (_Float16)acc[mi][ni][r];
      }
    }
  } else {
#pragma unroll
    for (int mi = 0; mi < 8; ++mi) {
      const int grow = mbase + wm * 128 + mi * 16 + qq * 4;
#pragma unroll
      for (int ni = 0; ni < 4; ++ni) {
        const int gcol = nbase + wn * 64 + ni * 16 + fr;
        const float bb = bias[gcol];
#pragma unroll
        for (int r = 0; r < 4; ++r)
          oC[(size_t)(grow + r) * 1024 + gcol] = acc[mi][ni][r] + bb;
      }
    }
  }
}

// ctx partials, global-direct: block = (bh, 256-row chunk), 4 waves x 64 rows.
// Lane holds 8x8 f32 outer-product acc (d0=(l&7)*8, e0=(l>>3)*8); k/v rows
// read straight from global (L2-resident, single pass, broadcast-coalesced
// 128B/row/wave). Block-reduces 4 wave partials in LDS -> one 64x64 partial.
// Same 512-partial layout as before -> ctx_reduce unchanged. Deterministic.
__global__ __launch_bounds__(256) void ctx_partial_kernel(
    const _Float16* __restrict__ kh, const _Float16* __restrict__ vh,
    float* __restrict__ ctxpart, float* __restrict__ colpart) {
  __shared__ float red[4 * 4096];  // 64KB: per-wave 64x64 partials
  __shared__ float credu[4 * 64];  // per-wave colsum partials
  const int t = threadIdx.x, l = t & 63, w = t >> 6;
  const int bh = blockIdx.x >> 5, ch = blockIdx.x & 31;
  const int d0 = (l & 7) * 8, e0 = (l >> 3) * 8;
  const size_t rowbase = ((size_t)bh * 8192 + ch * 256 + w * 64) * 64;
  const _Float16* kp = kh + rowbase;
  const _Float16* vp = vh + rowbase;
  f32x4 acc[8][2] = {};
  float cacc[8] = {};
  for (int n = 0; n < 64; ++n) {
    half8 k8 = *(const half8*)(kp + (size_t)n * 64 + d0);
    half8 v8 = *(const half8*)(vp + (size_t)n * 64 + e0);
    float e[8];
    f32x4 v4[2];
#pragma unroll
    for (int i = 0; i < 8; ++i) e[i] = __expf((float)k8[i]);
#pragma unroll
    for (int j = 0; j < 8; ++j) v4[j >> 2][j & 3] = (float)v8[j];
#pragma unroll
    for (int i = 0; i < 8; ++i) {
      cacc[i] += e[i];  // valid per-d sums on lanes l<8 (e0==0 group)
      acc[i][0] += v4[0] * e[i];
      acc[i][1] += v4[1] * e[i];
    }
  }
#pragma unroll
  for (int i = 0; i < 8; ++i) {
    *(f32x4*)&red[w * 4096 + (d0 + i) * 64 + e0] = acc[i][0];
    *(f32x4*)&red[w * 4096 + (d0 + i) * 64 + e0 + 4] = acc[i][1];
  }
  if (l < 8) {
#pragma unroll
    for (int i = 0; i < 8; ++i) credu[w * 64 + l * 8 + i] = cacc[i];
  }
  __syncthreads();
  float* cp = ctxpart + (size_t)blockIdx.x * 4096;
#pragma unroll
  for (int s = 0; s < 4; ++s) {
    const int r = t * 16 + s * 4;
    f32x4 sum = *(const f32x4*)&red[r];
    sum += *(const f32x4*)&red[4096 + r];
    sum += *(const f32x4*)&red[8192 + r];
    sum += *(const f32x4*)&red[12288 + r];
    *(f32x4*)&cp[r] = sum;
  }
  if (t < 64)
    colpart[blockIdx.x * 64 + t] =
        credu[t] + credu[64 + t] + credu[128 + t] + credu[192 + t];
}

// ctx[bh][d][e] = (sum_c ctxpart) / (sum_c colpart[d])
__global__ void ctx_reduce_kernel(const float* __restrict__ ctxpart,
                                  const float* __restrict__ colpart,
                                  float* __restrict__ ctx) {
  int i = blockIdx.x * 256 + threadIdx.x;  // 65536 total
  int bh = i >> 12, r = i & 4095, d = r >> 6;
  float s = 0.f, v = 0.f;
  for (int c = 0; c < 32; ++c) {
    s += colpart[((size_t)bh * 32 + c) * 64 + d];
    v += ctxpart[((size_t)bh * 32 + c) * 4096 + r];
  }
  ctx[i] = v / s;
}

// Per (bh, 128-row chunk): stage q logits, softmax rows in LDS (wave=row),
// then out[n][e] = sum_d softq[n][d]*ctx[d][e]; write attn f16 [16384][512].
__global__ __launch_bounds__(256) void qctx_kernel(const _Float16* __restrict__ qh,
                                                   const float* __restrict__ ctx,
                                                   _Float16* __restrict__ attn) {
  __shared__ float sq[128 * 64];
  __shared__ float sc[64 * 64];
  const int t = threadIdx.x;
  const int bh = blockIdx.x >> 6, ch = blockIdx.x & 63;
  const int b = bh >> 3, h = bh & 7;
  const _Float16* qb = qh + ((size_t)bh * 8192 + ch * 128) * 64;
  for (int i = t; i < 2048; i += 256) {
    half4 a = ((const half4*)qb)[i];
    f32x4 f = {(float)a[0], (float)a[1], (float)a[2], (float)a[3]};
    *(f32x4*)&sq[i * 4] = f;
  }
  const float* cb = ctx + (size_t)bh * 4096;
  for (int i = t; i < 1024; i += 256)
    *(f32x4*)&sc[i * 4] = *(const f32x4*)&cb[i * 4];
  __syncthreads();
  const int w = t >> 6, l = t & 63;
  for (int r = w * 32; r < w * 32 + 32; ++r) {
    float e = __expf(sq[r * 64 + l]);
    float s = e;
#pragma unroll
    for (int off = 1; off < 64; off <<= 1) s += __shfl_xor(s, off, 64);
    sq[r * 64 + l] = e / s;
  }
  __syncthreads();
  // d-blocked, vectorized: 4 c-rows + 8 q-f32x4 reads per d0 step
  const int e0 = (t & 15) * 4, n0 = (t >> 4) * 8;
  float acc[8][4] = {};
  for (int d04 = 0; d04 < 16; ++d04) {
    const int d0 = d04 * 4;
    f32x4 c4[4];
#pragma unroll
    for (int dd = 0; dd < 4; ++dd) c4[dd] = *(const f32x4*)&sc[(d0 + dd) * 64 + e0];
#pragma unroll
    for (int i = 0; i < 8; ++i) {
      f32x4 qv = *(const f32x4*)&sq[(n0 + i) * 64 + d0];
#pragma unroll
      for (int dd = 0; dd < 4; ++dd)
#pragma unroll
        for (int j = 0; j < 4; ++j) acc[i][j] += qv[dd] * c4[dd][j];
    }
  }
#pragma unroll
  for (int i = 0; i < 8; ++i) {
    int n = ch * 128 + n0 + i;
    half4 o = {(_Float16)acc[i][0], (_Float16)acc[i][1], (_Float16)acc[i][2],
               (_Float16)acc[i][3]};
    *(half4*)&attn[(size_t)(b * 8192 + n) * 512 + h * 64 + e0] = o;
  }
}

extern "C" void kernel_launch(void* const* d_in, const int* in_sizes, int n_in,
                              void* d_out, int out_size, void* d_ws, size_t ws_size,
                              hipStream_t stream) {
  const float* x = (const float*)d_in[0];
  const float* Wqkv = (const float*)d_in[1];
  const float* Wout = (const float*)d_in[2];
  const float* bout = (const float*)d_in[3];
  float* out = (float*)d_out;
  char* ws = (char*)d_ws;

  _Float16* xb = (_Float16*)(ws + WS_XB);
  _Float16* wqkvT = (_Float16*)(ws + WS_WQKVT);
  _Float16* woutT = (_Float16*)(ws + WS_WOUTT);
  _Float16* qh = (_Float16*)(ws + WS_QH);
  _Float16* kh = (_Float16*)(ws + WS_KH);
  _Float16* vh = (_Float16*)(ws + WS_VH);
  _Float16* attn = (_Float16*)(ws + WS_ATTN);
  float* ctxpart = (float*)(ws + WS_CTXPART);
  float* colpart = (float*)(ws + WS_COLPART);
  float* ctx = (float*)(ws + WS_CTX);

  // 1) fused converts (x cvt + both weight transposes)
  prep_kernel<<<24576, 256, 0, stream>>>(x, Wqkv, Wout, xb, wqkvT, woutT);
  // 2) qkv projection (M=16384,N=1536,K=1024), scattered to per-head q/k/v
  gemm8p<0><<<384, 512, 0, stream>>>(xb, wqkvT, 1024, 6, qh, kh, vh, nullptr,
                                     nullptr);
  // 3) context = exp(k)^T v partials + colsums, then deterministic reduce
  ctx_partial_kernel<<<512, 256, 0, stream>>>(kh, vh, ctxpart, colpart);
  ctx_reduce_kernel<<<256, 256, 0, stream>>>(ctxpart, colpart, ctx);
  // 4) softmax(q) @ ctx -> attn
  qctx_kernel<<<1024, 256, 0, stream>>>(qh, ctx, attn);
  // 5) output projection + bias (M=16384,N=1024,K=512)
  gemm8p<1><<<256, 512, 0, stream>>>(attn, woutT, 512, 4, nullptr, nullptr,
                                     nullptr, out, bout);
}

// Round 7
// 177.414 us; speedup vs baseline: 1.2862x; 1.0926x over previous
//
#include <hip/hip_runtime.h>
#include <stdint.h>

// LinearAttention: x[2,8192,1024] -> qkv proj -> per-head softmaxes ->
// context = softmax_n(k)^T v -> out = softmax_d(q) @ ctx -> @ W_out + b.
//
// R7 GEMM: 128x128 tile, BK=64, 4 waves (256 thr), 64KB LDS -> 2 blocks/CU
// co-resident (TLP covers barrier/vmcnt stalls that 1-block/CU R3-R5
// couldn't hide; also exact-round grids: 1536=3x512, 1024=2x512, no tail).
// 2-phase loop, region-safety: all reads ph0 from cur; both stages ph0 ->
// other (prev tile's reads of `other` drained by its ph1 lgkmcnt(0) before
// BAR_b); ph1 = lgkmcnt(0)+vmcnt(0); BAR; MFMA2.
// ctx_partial: reverted to R4 LDS-staged version (R6's global-direct was a
// latency chain, ~+24us). qctx: d-blocked vectorized (R5/R6-validated).

typedef _Float16 half4 __attribute__((ext_vector_type(4)));
typedef _Float16 half8 __attribute__((ext_vector_type(8)));
typedef float f32x4 __attribute__((ext_vector_type(4)));

// ---- workspace byte offsets (total ~113.6 MB) ----
#define WS_XB 0UL             // x as f16          [16384][1024]   33.55MB
#define WS_WQKVT 33554432UL   // W_qkv^T f16       [1536][1024]     3.15MB
#define WS_WOUTT 36700160UL   // W_out^T f16       [1024][512]      1.05MB
#define WS_QH 37748736UL      // q logits f16      [16][8192][64]  16.78MB
#define WS_KH 54525952UL      // k logits f16      [16][8192][64]  16.78MB
#define WS_VH 71303168UL      // v f16             [16][8192][64]  16.78MB
#define WS_ATTN 88080384UL    // attn out f16      [16384][512]    16.78MB
#define WS_CTXPART 104857600UL// ctx partials f32  [512][4096]      8.39MB
#define WS_COLPART 113246208UL// colsum partials   [512][64]        0.13MB
#define WS_CTX 113377280UL    // ctx f32           [16][64][64]     0.26MB

__device__ __forceinline__ void gld16(const void* g, void* l) {
  // async global->LDS, 16B per lane; LDS dest = wave-uniform base + lane*16
  __builtin_amdgcn_global_load_lds(
      (const __attribute__((address_space(1))) unsigned int*)g,
      (__attribute__((address_space(3))) unsigned int*)l, 16, 0, 0);
}

// Fused prep: cvt x (f32->f16), transpose+cvt W_qkv, transpose+cvt W_out.
__global__ void prep_kernel(const float* __restrict__ x,
                            const float* __restrict__ Wqkv,
                            const float* __restrict__ Wout,
                            _Float16* __restrict__ xb,
                            _Float16* __restrict__ wqkvT,
                            _Float16* __restrict__ woutT) {
  const int blk = blockIdx.x;
  if (blk < 16384) {
    int i = blk * 256 + threadIdx.x;  // 4 f32 per thread
    f32x4 v = *(const f32x4*)(x + (size_t)i * 4);
    half4 h = {(_Float16)v[0], (_Float16)v[1], (_Float16)v[2], (_Float16)v[3]};
    *(half4*)(xb + (size_t)i * 4) = h;
  } else if (blk < 16384 + 6144) {
    int i = (blk - 16384) * 256 + threadIdx.x;  // [0, 1536*1024)
    int c = i >> 10, r = i & 1023;
    wqkvT[i] = (_Float16)Wqkv[(size_t)r * 1536 + c];
  } else {
    int i = (blk - 16384 - 6144) * 256 + threadIdx.x;  // [0, 1024*512)
    int c = i >> 9, r = i & 511;
    woutT[i] = (_Float16)Wout[(size_t)r * 1024 + c];
  }
}

// ---------------- 128x128 BK=64 co-resident GEMM ----------------
// A[M][K] f16 row-major, BT[N][K] f16 row-major. 256 threads = 4 waves (2Mx2N),
// per-wave output 64x64 (acc[4][4]). LDS: 2 dbuf x (A 16KB + B 16KB) = 64KB.
// Tile layout [128 rows][128B], XOR swizzle byte ^= ((row&7)<<4); staged
// linearly via global_load_lds with inverse-swizzled global source column.

// stage one full 128x64-f16 tile region = 4 sweeps x 1 gld16/thread
__device__ __forceinline__ void stage_tile(const _Float16* __restrict__ G, int K,
                                           int rowbase, int kt, char* region,
                                           int t) {
  char* wbase = region + (t & ~63) * 16;  // + lane*16 done by HW
#pragma unroll
  for (int q = 0; q < 4; ++q) {
    const int row = q * 32 + (t >> 3);
    const int col8 = ((t & 7) ^ (row & 7)) * 8;  // inverse-swizzled f16 col
    gld16(G + (size_t)(rowbase + row) * K + kt + col8, wbase + q * 4096);
  }
}

// EPI 0: scatter qkv -> per-head q/k/v f16. EPI 1: +bias, f32 out ldc=1024.
template <int EPI>
__global__ __launch_bounds__(256, 2) void gemm128(
    const _Float16* __restrict__ A, const _Float16* __restrict__ BT, int K,
    int NTN, _Float16* __restrict__ oQ, _Float16* __restrict__ oK,
    _Float16* __restrict__ oV, float* __restrict__ oC,
    const float* __restrict__ bias) {
  __shared__ char lds[65536];
  const int t = threadIdx.x;
  const int l = t & 63, w = t >> 6;
  const int wm = w >> 1, wn = w & 1;  // wave -> 64x64 quadrant
  const int fr = l & 15, qq = l >> 4;
  const int swzx = (fr & 7) << 4;

  // T1: bijective XCD chunking (nwg % 8 == 0), tileM-major within chunk
  const int nwg = gridDim.x;
  const int cpx = nwg >> 3;
  const int wg = (blockIdx.x & 7) * cpx + (blockIdx.x >> 3);
  const int tileM = wg / NTN, tileN = wg - tileM * NTN;
  const int mbase = tileM * 128, nbase = tileN * 128;

  const int NT = K >> 6;
  f32x4 acc[4][4] = {};
  half8 a[4][2], b[4][2];

  // stage both operands of K-tile `tile` into buffer (tile&1)
  auto STG = [&](int tile) {
    int kt = tile * 64;
    if (kt > K - 64) kt = K - 64;  // tail clamp: identical issue counts
    char* base = lds + ((tile & 1) << 15);
    stage_tile(A, K, mbase, kt, base, t);          // 4 loads
    stage_tile(BT, K, nbase, kt, base + 16384, t); // 4 loads
  };

  // prologue: tile0 + tile1 (16 loads/thread); vmcnt(8) -> tile0 resident
  STG(0);
  STG(1);
  asm volatile("s_waitcnt vmcnt(8)" ::: "memory");
  __builtin_amdgcn_s_barrier();

  for (int t2 = 0; t2 < NT; ++t2) {
    const char* ldsA = lds + ((t2 & 1) << 15);
    const char* ldsB = ldsA + 16384;
    // ph0: stage tile t2+1 -> other buffer (prev readers drained at ph1's
    // lgkmcnt(0) before BAR_b); then all frag reads from cur.
    STG(t2 + 1);
#pragma unroll
    for (int mi = 0; mi < 4; ++mi)
#pragma unroll
      for (int kk = 0; kk < 2; ++kk) {
        int off = (wm * 64 + mi * 16 + fr) * 128 + ((kk * 64 + qq * 16) ^ swzx);
        a[mi][kk] = *(const half8*)(ldsA + off);
      }
#pragma unroll
    for (int ni = 0; ni < 4; ++ni)
#pragma unroll
      for (int kk = 0; kk < 2; ++kk) {
        int off = (wn * 64 + ni * 16 + fr) * 128 + ((kk * 64 + qq * 16) ^ swzx);
        b[ni][kk] = *(const half8*)(ldsB + off);
      }
    __builtin_amdgcn_s_barrier();  // BAR_a
    __builtin_amdgcn_s_setprio(1);
#pragma unroll
    for (int mi = 0; mi < 4; ++mi)
#pragma unroll
      for (int ni = 0; ni < 2; ++ni)
#pragma unroll
        for (int kk = 0; kk < 2; ++kk)
          acc[mi][ni] = __builtin_amdgcn_mfma_f32_16x16x32_f16(
              a[mi][kk], b[ni][kk], acc[mi][ni], 0, 0, 0);
    __builtin_amdgcn_s_setprio(0);
    // ph1: drain this tile's ds_reads (b23 pending only -> cheap) so the
    // next iteration's STG->other is race-free; drain stage loads (t2+1).
    asm volatile("s_waitcnt vmcnt(0) lgkmcnt(0)" ::: "memory");
    __builtin_amdgcn_s_barrier();  // BAR_b
    __builtin_amdgcn_s_setprio(1);
#pragma unroll
    for (int mi = 0; mi < 4; ++mi)
#pragma unroll
      for (int ni = 2; ni < 4; ++ni)
#pragma unroll
        for (int kk = 0; kk < 2; ++kk)
          acc[mi][ni] = __builtin_amdgcn_mfma_f32_16x16x32_f16(
              a[mi][kk], b[ni][kk], acc[mi][ni], 0, 0, 0);
    __builtin_amdgcn_s_setprio(0);
  }

  // C/D layout: col = lane&15 (=fr), row = (lane>>4)*4 + reg (=qq*4+r)
  if (EPI == 0) {
#pragma unroll
    for (int mi = 0; mi < 4; ++mi) {
      const int grow = mbase + wm * 64 + mi * 16 + qq * 4;
      const int bidx = grow >> 13, n = grow & 8191;
#pragma unroll
      for (int ni = 0; ni < 4; ++ni) {
        const int gcol = nbase + wn * 64 + ni * 16 + fr;
        const int which = gcol >> 9, h = (gcol >> 6) & 7, d = gcol & 63;
        _Float16* dst = (which == 0) ? oQ : ((which == 1) ? oK : oV);
        const size_t base = ((size_t)((bidx << 3) + h) * 8192 + n) * 64 + d;
#pragma unroll
        for (int r = 0; r < 4; ++r)
          dst[base + (size_t)r * 64] = (_Float16)acc[mi][ni][r];
      }
    }
  } else {
#pragma unroll
    for (int mi = 0; mi < 4; ++mi) {
      const int grow = mbase + wm * 64 + mi * 16 + qq * 4;
#pragma unroll
      for (int ni = 0; ni < 4; ++ni) {
        const int gcol = nbase + wn * 64 + ni * 16 + fr;
        const float bb = bias[gcol];
#pragma unroll
        for (int r = 0; r < 4; ++r)
          oC[(size_t)(grow + r) * 1024 + gcol] = acc[mi][ni][r] + bb;
      }
    }
  }
}

// Per (bh, 256-row chunk): stage exp(k) and v (f16->f32) in LDS, accumulate
// 64x64 partial ctx + per-column partial sums. No atomics -> deterministic.
// (R4-measured version; R6's global-direct variant was latency-bound.)
__global__ __launch_bounds__(256) void ctx_partial_kernel(
    const _Float16* __restrict__ kh, const _Float16* __restrict__ vh,
    float* __restrict__ ctxpart, float* __restrict__ colpart) {
  __shared__ float se[128 * 64];
  __shared__ float sv[128 * 64];
  const int t = threadIdx.x;
  const int bh = blockIdx.x >> 5, ch = blockIdx.x & 31;
  const size_t rowbase = ((size_t)bh * 8192 + ch * 256) * 64;
  const int d0 = (t & 15) * 4, e0 = (t >> 4) * 4;
  float acc[4][4] = {};
  float colacc = 0.f;
  for (int sub = 0; sub < 2; ++sub) {
    const _Float16* kp = kh + rowbase + (size_t)sub * (128 * 64);
    const _Float16* vp = vh + rowbase + (size_t)sub * (128 * 64);
    __syncthreads();
    for (int i = t; i < 2048; i += 256) {
      half4 a = ((const half4*)kp)[i];
      half4 b = ((const half4*)vp)[i];
      f32x4 fa = {__expf((float)a[0]), __expf((float)a[1]),
                  __expf((float)a[2]), __expf((float)a[3])};
      f32x4 fb = {(float)b[0], (float)b[1], (float)b[2], (float)b[3]};
      *(f32x4*)&se[i * 4] = fa;
      *(f32x4*)&sv[i * 4] = fb;
    }
    __syncthreads();
    if (t < 64) {
      for (int n = 0; n < 128; ++n) colacc += se[n * 64 + t];
    }
    for (int n = 0; n < 128; ++n) {
      f32x4 a = *(const f32x4*)&se[n * 64 + d0];
      f32x4 b = *(const f32x4*)&sv[n * 64 + e0];
#pragma unroll
      for (int i2 = 0; i2 < 4; ++i2)
#pragma unroll
        for (int j = 0; j < 4; ++j) acc[i2][j] += a[i2] * b[j];
    }
  }
  float* cp = ctxpart + (size_t)blockIdx.x * 4096;
#pragma unroll
  for (int i2 = 0; i2 < 4; ++i2)
#pragma unroll
    for (int j = 0; j < 4; ++j) cp[(d0 + i2) * 64 + e0 + j] = acc[i2][j];
  if (t < 64) colpart[blockIdx.x * 64 + t] = colacc;
}

// ctx[bh][d][e] = (sum_c ctxpart) / (sum_c colpart[d])
__global__ void ctx_reduce_kernel(const float* __restrict__ ctxpart,
                                  const float* __restrict__ colpart,
                                  float* __restrict__ ctx) {
  int i = blockIdx.x * 256 + threadIdx.x;  // 65536 total
  int bh = i >> 12, r = i & 4095, d = r >> 6;
  float s = 0.f, v = 0.f;
  for (int c = 0; c < 32; ++c) {
    s += colpart[((size_t)bh * 32 + c) * 64 + d];
    v += ctxpart[((size_t)bh * 32 + c) * 4096 + r];
  }
  ctx[i] = v / s;
}

// Per (bh, 128-row chunk): stage q logits, softmax rows in LDS (wave=row),
// then out[n][e] = sum_d softq[n][d]*ctx[d][e]; write attn f16 [16384][512].
__global__ __launch_bounds__(256) void qctx_kernel(const _Float16* __restrict__ qh,
                                                   const float* __restrict__ ctx,
                                                   _Float16* __restrict__ attn) {
  __shared__ float sq[128 * 64];
  __shared__ float sc[64 * 64];
  const int t = threadIdx.x;
  const int bh = blockIdx.x >> 6, ch = blockIdx.x & 63;
  const int b = bh >> 3, h = bh & 7;
  const _Float16* qb = qh + ((size_t)bh * 8192 + ch * 128) * 64;
  for (int i = t; i < 2048; i += 256) {
    half4 a = ((const half4*)qb)[i];
    f32x4 f = {(float)a[0], (float)a[1], (float)a[2], (float)a[3]};
    *(f32x4*)&sq[i * 4] = f;
  }
  const float* cb = ctx + (size_t)bh * 4096;
  for (int i = t; i < 1024; i += 256)
    *(f32x4*)&sc[i * 4] = *(const f32x4*)&cb[i * 4];
  __syncthreads();
  const int w = t >> 6, l = t & 63;
  for (int r = w * 32; r < w * 32 + 32; ++r) {
    float e = __expf(sq[r * 64 + l]);
    float s = e;
#pragma unroll
    for (int off = 1; off < 64; off <<= 1) s += __shfl_xor(s, off, 64);
    sq[r * 64 + l] = e / s;
  }
  __syncthreads();
  // d-blocked, vectorized: 4 c-rows + 8 q-f32x4 reads per d0 step
  const int e0 = (t & 15) * 4, n0 = (t >> 4) * 8;
  float acc[8][4] = {};
  for (int d04 = 0; d04 < 16; ++d04) {
    const int d0 = d04 * 4;
    f32x4 c4[4];
#pragma unroll
    for (int dd = 0; dd < 4; ++dd) c4[dd] = *(const f32x4*)&sc[(d0 + dd) * 64 + e0];
#pragma unroll
    for (int i = 0; i < 8; ++i) {
      f32x4 qv = *(const f32x4*)&sq[(n0 + i) * 64 + d0];
#pragma unroll
      for (int dd = 0; dd < 4; ++dd)
#pragma unroll
        for (int j = 0; j < 4; ++j) acc[i][j] += qv[dd] * c4[dd][j];
    }
  }
#pragma unroll
  for (int i = 0; i < 8; ++i) {
    int n = ch * 128 + n0 + i;
    half4 o = {(_Float16)acc[i][0], (_Float16)acc[i][1], (_Float16)acc[i][2],
               (_Float16)acc[i][3]};
    *(half4*)&attn[(size_t)(b * 8192 + n) * 512 + h * 64 + e0] = o;
  }
}

extern "C" void kernel_launch(void* const* d_in, const int* in_sizes, int n_in,
                              void* d_out, int out_size, void* d_ws, size_t ws_size,
                              hipStream_t stream) {
  const float* x = (const float*)d_in[0];
  const float* Wqkv = (const float*)d_in[1];
  const float* Wout = (const float*)d_in[2];
  const float* bout = (const float*)d_in[3];
  float* out = (float*)d_out;
  char* ws = (char*)d_ws;

  _Float16* xb = (_Float16*)(ws + WS_XB);
  _Float16* wqkvT = (_Float16*)(ws + WS_WQKVT);
  _Float16* woutT = (_Float16*)(ws + WS_WOUTT);
  _Float16* qh = (_Float16*)(ws + WS_QH);
  _Float16* kh = (_Float16*)(ws + WS_KH);
  _Float16* vh = (_Float16*)(ws + WS_VH);
  _Float16* attn = (_Float16*)(ws + WS_ATTN);
  float* ctxpart = (float*)(ws + WS_CTXPART);
  float* colpart = (float*)(ws + WS_COLPART);
  float* ctx = (float*)(ws + WS_CTX);

  // 1) fused converts (x cvt + both weight transposes)
  prep_kernel<<<24576, 256, 0, stream>>>(x, Wqkv, Wout, xb, wqkvT, woutT);
  // 2) qkv projection (M=16384,N=1536,K=1024), scattered to per-head q/k/v
  gemm128<0><<<1536, 256, 0, stream>>>(xb, wqkvT, 1024, 12, qh, kh, vh,
                                       nullptr, nullptr);
  // 3) context = exp(k)^T v partials + colsums, then deterministic reduce
  ctx_partial_kernel<<<512, 256, 0, stream>>>(kh, vh, ctxpart, colpart);
  ctx_reduce_kernel<<<256, 256, 0, stream>>>(ctxpart, colpart, ctx);
  // 4) softmax(q) @ ctx -> attn
  qctx_kernel<<<1024, 256, 0, stream>>>(qh, ctx, attn);
  // 5) output projection + bias (M=16384,N=1024,K=512)
  gemm128<1><<<1024, 256, 0, stream>>>(attn, woutT, 512, 8, nullptr, nullptr,
                                       nullptr, out, bout);
}

// Round 8
// 157.327 us; speedup vs baseline: 1.4504x; 1.1277x over previous
//
#include <hip/hip_runtime.h>
#include <stdint.h>

// LinearAttention: x[2,8192,1024] -> qkv proj -> per-head softmaxes ->
// context = softmax_n(k)^T v -> out = softmax_d(q) @ ctx -> @ W_out + b.
//
// R8 fusions (GEMM structure = R7-measured, 814 TF):
//  - softmax(q) fused into GEMM1 epilogue (wave holds full head row) ->
//    softq f16 [16384][512]; q logits never stored.
//  - exp(k) fused into GEMM1 epilogue -> ekh f16; ctx_partial skips exp.
//  - out = softq @ (ctx @ W_out) via per-batch CW^T precompute (ctxw kernel);
//    qctx kernel deleted (its VALU matvec == GEMM2's MFMA FLOPs).
// GEMM: 128x128 tile, BK=64, 4 waves, 64KB LDS -> 2 blocks/CU co-resident.

typedef _Float16 half4 __attribute__((ext_vector_type(4)));
typedef _Float16 half8 __attribute__((ext_vector_type(8)));
typedef float f32x4 __attribute__((ext_vector_type(4)));

// ---- workspace byte offsets ----
#define WS_XB 0UL             // x as f16          [16384][1024]   33.55MB
#define WS_WQKVT 33554432UL   // W_qkv^T f16       [1536][1024]     3.15MB
#define WS_CWT 37748736UL     // CW^T f16          [2][1024][512]   2.10MB
#define WS_EKH 54525952UL     // exp(k) f16        [16][8192][64]  16.78MB
#define WS_VH 71303168UL      // v f16             [16][8192][64]  16.78MB
#define WS_SQ 88080384UL      // softmax(q) f16    [16384][512]    16.78MB
#define WS_CTXPART 104857600UL// ctx partials f32  [512][4096]      8.39MB
#define WS_COLPART 113246208UL// colsum partials   [512][64]        0.13MB
#define WS_CTX 113377280UL    // ctx f32           [16][64][64]     0.26MB

__device__ __forceinline__ void gld16(const void* g, void* l) {
  // async global->LDS, 16B per lane; LDS dest = wave-uniform base + lane*16
  __builtin_amdgcn_global_load_lds(
      (const __attribute__((address_space(1))) unsigned int*)g,
      (__attribute__((address_space(3))) unsigned int*)l, 16, 0, 0);
}

// Fused prep: cvt x (f32->f16), transpose+cvt W_qkv.
__global__ void prep_kernel(const float* __restrict__ x,
                            const float* __restrict__ Wqkv,
                            _Float16* __restrict__ xb,
                            _Float16* __restrict__ wqkvT) {
  const int blk = blockIdx.x;
  if (blk < 16384) {
    int i = blk * 256 + threadIdx.x;  // 4 f32 per thread
    f32x4 v = *(const f32x4*)(x + (size_t)i * 4);
    half4 h = {(_Float16)v[0], (_Float16)v[1], (_Float16)v[2], (_Float16)v[3]};
    *(half4*)(xb + (size_t)i * 4) = h;
  } else {
    int i = (blk - 16384) * 256 + threadIdx.x;  // [0, 1536*1024)
    int c = i >> 10, r = i & 1023;
    wqkvT[i] = (_Float16)Wqkv[(size_t)r * 1536 + c];
  }
}

// ---------------- 128x128 BK=64 co-resident GEMM (R7-measured) -------------
// A[M][K] f16 row-major, BT[N][K] f16 row-major. 256 threads = 4 waves (2Mx2N),
// per-wave output 64x64 (acc[4][4]). LDS: 2 dbuf x (A 16KB + B 16KB) = 64KB.
// Tile layout [128 rows][128B], XOR swizzle byte ^= ((row&7)<<4); staged
// linearly via global_load_lds with inverse-swizzled global source column.

// stage one full 128x64-f16 tile region = 4 sweeps x 1 gld16/thread
__device__ __forceinline__ void stage_tile(const _Float16* __restrict__ G, int K,
                                           int rowbase, int kt, char* region,
                                           int t) {
  char* wbase = region + (t & ~63) * 16;  // + lane*16 done by HW
#pragma unroll
  for (int q = 0; q < 4; ++q) {
    const int row = q * 32 + (t >> 3);
    const int col8 = ((t & 7) ^ (row & 7)) * 8;  // inverse-swizzled f16 col
    gld16(G + (size_t)(rowbase + row) * K + kt + col8, wbase + q * 4096);
  }
}

// EPI 0: softmax(q)->oQ[16384][512]; exp(k)->oK per-head; v->oV per-head.
// EPI 1: +bias, f32 out ldc=1024 (A=softq, BT=CW^T per batch via bstride).
template <int EPI>
__global__ __launch_bounds__(256, 2) void gemm128(
    const _Float16* __restrict__ A, const _Float16* __restrict__ BT, int K,
    int NTN, int bstride, _Float16* __restrict__ oQ, _Float16* __restrict__ oK,
    _Float16* __restrict__ oV, float* __restrict__ oC,
    const float* __restrict__ bias) {
  __shared__ char lds[65536];
  const int t = threadIdx.x;
  const int l = t & 63, w = t >> 6;
  const int wm = w >> 1, wn = w & 1;  // wave -> 64x64 quadrant
  const int fr = l & 15, qq = l >> 4;
  const int swzx = (fr & 7) << 4;

  // T1: bijective XCD chunking (nwg % 8 == 0), tileM-major within chunk
  const int nwg = gridDim.x;
  const int cpx = nwg >> 3;
  const int wg = (blockIdx.x & 7) * cpx + (blockIdx.x >> 3);
  const int tileM = wg / NTN, tileN = wg - tileM * NTN;
  const int mbase = tileM * 128, nbase = tileN * 128;
  BT += (size_t)(tileM >> 6) * bstride;  // per-batch B (0 for GEMM1)

  const int NT = K >> 6;
  f32x4 acc[4][4] = {};
  half8 a[4][2], b[4][2];

  // stage both operands of K-tile `tile` into buffer (tile&1)
  auto STG = [&](int tile) {
    int kt = tile * 64;
    if (kt > K - 64) kt = K - 64;  // tail clamp: identical issue counts
    char* base = lds + ((tile & 1) << 15);
    stage_tile(A, K, mbase, kt, base, t);          // 4 loads
    stage_tile(BT, K, nbase, kt, base + 16384, t); // 4 loads
  };

  // prologue: tile0 + tile1 (16 loads/thread); vmcnt(8) -> tile0 resident
  STG(0);
  STG(1);
  asm volatile("s_waitcnt vmcnt(8)" ::: "memory");
  __builtin_amdgcn_s_barrier();

  for (int t2 = 0; t2 < NT; ++t2) {
    const char* ldsA = lds + ((t2 & 1) << 15);
    const char* ldsB = ldsA + 16384;
    // ph0: stage tile t2+1 -> other buffer (prev readers drained at ph1's
    // lgkmcnt(0) before BAR_b); then all frag reads from cur.
    STG(t2 + 1);
#pragma unroll
    for (int mi = 0; mi < 4; ++mi)
#pragma unroll
      for (int kk = 0; kk < 2; ++kk) {
        int off = (wm * 64 + mi * 16 + fr) * 128 + ((kk * 64 + qq * 16) ^ swzx);
        a[mi][kk] = *(const half8*)(ldsA + off);
      }
#pragma unroll
    for (int ni = 0; ni < 4; ++ni)
#pragma unroll
      for (int kk = 0; kk < 2; ++kk) {
        int off = (wn * 64 + ni * 16 + fr) * 128 + ((kk * 64 + qq * 16) ^ swzx);
        b[ni][kk] = *(const half8*)(ldsB + off);
      }
    __builtin_amdgcn_s_barrier();  // BAR_a
    __builtin_amdgcn_s_setprio(1);
#pragma unroll
    for (int mi = 0; mi < 4; ++mi)
#pragma unroll
      for (int ni = 0; ni < 2; ++ni)
#pragma unroll
        for (int kk = 0; kk < 2; ++kk)
          acc[mi][ni] = __builtin_amdgcn_mfma_f32_16x16x32_f16(
              a[mi][kk], b[ni][kk], acc[mi][ni], 0, 0, 0);
    __builtin_amdgcn_s_setprio(0);
    // ph1: drain this tile's ds_reads so next iter's STG->other is race-free;
    // drain stage loads (t2+1).
    asm volatile("s_waitcnt vmcnt(0) lgkmcnt(0)" ::: "memory");
    __builtin_amdgcn_s_barrier();  // BAR_b
    __builtin_amdgcn_s_setprio(1);
#pragma unroll
    for (int mi = 0; mi < 4; ++mi)
#pragma unroll
      for (int ni = 2; ni < 4; ++ni)
#pragma unroll
        for (int kk = 0; kk < 2; ++kk)
          acc[mi][ni] = __builtin_amdgcn_mfma_f32_16x16x32_f16(
              a[mi][kk], b[ni][kk], acc[mi][ni], 0, 0, 0);
    __builtin_amdgcn_s_setprio(0);
  }

  // C/D layout: col = lane&15 (=fr), row = (lane>>4)*4 + reg (=qq*4+r)
  if (EPI == 0) {
    // wave's 64-col range is 64-aligned -> single `which`, single head
    const int gcol0 = nbase + wn * 64;
    const int which = gcol0 >> 9;
    if (which == 0) {
      // fused softmax over head dim (4 in-reg + shfl_xor<16), store softq
#pragma unroll
      for (int mi = 0; mi < 4; ++mi) {
        const int grow = mbase + wm * 64 + mi * 16 + qq * 4;
        float e[4][4], rs[4];
#pragma unroll
        for (int r = 0; r < 4; ++r) {
          float s = 0.f;
#pragma unroll
          for (int ni = 0; ni < 4; ++ni) {
            e[ni][r] = __expf(acc[mi][ni][r]);
            s += e[ni][r];
          }
#pragma unroll
          for (int off = 1; off < 16; off <<= 1) s += __shfl_xor(s, off, 64);
          rs[r] = 1.f / s;
        }
#pragma unroll
        for (int ni = 0; ni < 4; ++ni) {
          const int gcol = gcol0 + ni * 16 + fr;
#pragma unroll
          for (int r = 0; r < 4; ++r)
            oQ[(size_t)(grow + r) * 512 + gcol] = (_Float16)(e[ni][r] * rs[r]);
        }
      }
    } else {
      // k: store exp(logit) f16 (range <= e^~6, f16-safe); v: plain f16
      _Float16* dst0 = (which == 1) ? oK : oV;
      const int h = (gcol0 >> 6) & 7;
#pragma unroll
      for (int mi = 0; mi < 4; ++mi) {
        const int grow = mbase + wm * 64 + mi * 16 + qq * 4;
        const int bidx = grow >> 13, n = grow & 8191;
        const size_t rb = ((size_t)((bidx << 3) + h) * 8192 + n) * 64;
#pragma unroll
        for (int ni = 0; ni < 4; ++ni) {
          const int d = ni * 16 + fr;
#pragma unroll
          for (int r = 0; r < 4; ++r) {
            float v = acc[mi][ni][r];
            if (which == 1) v = __expf(v);
            dst0[rb + (size_t)r * 64 + d] = (_Float16)v;
          }
        }
      }
    }
  } else {
#pragma unroll
    for (int mi = 0; mi < 4; ++mi) {
      const int grow = mbase + wm * 64 + mi * 16 + qq * 4;
#pragma unroll
      for (int ni = 0; ni < 4; ++ni) {
        const int gcol = nbase + wn * 64 + ni * 16 + fr;
        const float bb = bias[gcol];
#pragma unroll
        for (int r = 0; r < 4; ++r)
          oC[(size_t)(grow + r) * 1024 + gcol] = acc[mi][ni][r] + bb;
      }
    }
  }
}

// Per (bh, 256-row chunk): stage ek and v (f16->f32) in LDS, accumulate
// 64x64 partial ctx + per-column partial sums. No atomics -> deterministic.
__global__ __launch_bounds__(256) void ctx_partial_kernel(
    const _Float16* __restrict__ ekh, const _Float16* __restrict__ vh,
    float* __restrict__ ctxpart, float* __restrict__ colpart) {
  __shared__ float se[128 * 64];
  __shared__ float sv[128 * 64];
  const int t = threadIdx.x;
  const int bh = blockIdx.x >> 5, ch = blockIdx.x & 31;
  const size_t rowbase = ((size_t)bh * 8192 + ch * 256) * 64;
  const int d0 = (t & 15) * 4, e0 = (t >> 4) * 4;
  float acc[4][4] = {};
  float colacc = 0.f;
  for (int sub = 0; sub < 2; ++sub) {
    const _Float16* kp = ekh + rowbase + (size_t)sub * (128 * 64);
    const _Float16* vp = vh + rowbase + (size_t)sub * (128 * 64);
    __syncthreads();
    for (int i = t; i < 2048; i += 256) {
      half4 a = ((const half4*)kp)[i];
      half4 b = ((const half4*)vp)[i];
      f32x4 fa = {(float)a[0], (float)a[1], (float)a[2], (float)a[3]};
      f32x4 fb = {(float)b[0], (float)b[1], (float)b[2], (float)b[3]};
      *(f32x4*)&se[i * 4] = fa;
      *(f32x4*)&sv[i * 4] = fb;
    }
    __syncthreads();
    if (t < 64) {
      for (int n = 0; n < 128; ++n) colacc += se[n * 64 + t];
    }
    for (int n = 0; n < 128; ++n) {
      f32x4 a = *(const f32x4*)&se[n * 64 + d0];
      f32x4 b = *(const f32x4*)&sv[n * 64 + e0];
#pragma unroll
      for (int i2 = 0; i2 < 4; ++i2)
#pragma unroll
        for (int j = 0; j < 4; ++j) acc[i2][j] += a[i2] * b[j];
    }
  }
  float* cp = ctxpart + (size_t)blockIdx.x * 4096;
#pragma unroll
  for (int i2 = 0; i2 < 4; ++i2)
#pragma unroll
    for (int j = 0; j < 4; ++j) cp[(d0 + i2) * 64 + e0 + j] = acc[i2][j];
  if (t < 64) colpart[blockIdx.x * 64 + t] = colacc;
}

// ctx[bh][d][e] = (sum_c ctxpart) / (sum_c colpart[d])
__global__ void ctx_reduce_kernel(const float* __restrict__ ctxpart,
                                  const float* __restrict__ colpart,
                                  float* __restrict__ ctx) {
  int i = blockIdx.x * 256 + threadIdx.x;  // 65536 total
  int bh = i >> 12, r = i & 4095, d = r >> 6;
  float s = 0.f, v = 0.f;
  for (int c = 0; c < 32; ++c) {
    s += colpart[((size_t)bh * 32 + c) * 64 + d];
    v += ctxpart[((size_t)bh * 32 + c) * 4096 + r];
  }
  ctx[i] = v / s;
}

// CW^T[b][o][h*64+d] = sum_e ctx[b*8+h][d][e] * Wout[h*64+e][o], f16 out.
// Block = (bh, d) (1024 blocks); thread handles o = t + j*256 (coalesced).
__global__ __launch_bounds__(256) void ctxw_kernel(const float* __restrict__ ctx,
                                                   const float* __restrict__ Wout,
                                                   _Float16* __restrict__ cwT) {
  const int blk = blockIdx.x;
  const int bh = blk >> 6, d = blk & 63;
  const int b = bh >> 3, h = bh & 7;
  const int t = threadIdx.x;
  const float* crow = ctx + (size_t)bh * 4096 + d * 64;
  float acc[4] = {};
#pragma unroll 8
  for (int e = 0; e < 64; ++e) {
    const float c = crow[e];
    const float* wr = Wout + (size_t)(h * 64 + e) * 1024 + t;
#pragma unroll
    for (int j = 0; j < 4; ++j) acc[j] += c * wr[j * 256];
  }
  _Float16* dst = cwT + (size_t)b * 524288 + (size_t)t * 512 + h * 64 + d;
#pragma unroll
  for (int j = 0; j < 4; ++j) dst[(size_t)j * 256 * 512] = (_Float16)acc[j];
}

extern "C" void kernel_launch(void* const* d_in, const int* in_sizes, int n_in,
                              void* d_out, int out_size, void* d_ws, size_t ws_size,
                              hipStream_t stream) {
  const float* x = (const float*)d_in[0];
  const float* Wqkv = (const float*)d_in[1];
  const float* Wout = (const float*)d_in[2];
  const float* bout = (const float*)d_in[3];
  float* out = (float*)d_out;
  char* ws = (char*)d_ws;

  _Float16* xb = (_Float16*)(ws + WS_XB);
  _Float16* wqkvT = (_Float16*)(ws + WS_WQKVT);
  _Float16* cwT = (_Float16*)(ws + WS_CWT);
  _Float16* ekh = (_Float16*)(ws + WS_EKH);
  _Float16* vh = (_Float16*)(ws + WS_VH);
  _Float16* sq = (_Float16*)(ws + WS_SQ);
  float* ctxpart = (float*)(ws + WS_CTXPART);
  float* colpart = (float*)(ws + WS_COLPART);
  float* ctx = (float*)(ws + WS_CTX);

  // 1) fused converts (x cvt + W_qkv transpose)
  prep_kernel<<<22528, 256, 0, stream>>>(x, Wqkv, xb, wqkvT);
  // 2) qkv projection + fused softmax(q)/exp(k) epilogue
  gemm128<0><<<1536, 256, 0, stream>>>(xb, wqkvT, 1024, 12, 0, sq, ekh, vh,
                                       nullptr, nullptr);
  // 3) context = ek^T v partials + colsums, then deterministic reduce
  ctx_partial_kernel<<<512, 256, 0, stream>>>(ekh, vh, ctxpart, colpart);
  ctx_reduce_kernel<<<256, 256, 0, stream>>>(ctxpart, colpart, ctx);
  // 4) CW^T = (ctx @ W_out)^T per batch
  ctxw_kernel<<<1024, 256, 0, stream>>>(ctx, Wout, cwT);
  // 5) out = softq @ CW + b  (M=16384,N=1024,K=512; B selected per batch)
  gemm128<1><<<1024, 256, 0, stream>>>(sq, cwT, 512, 8, 524288, nullptr,
                                       nullptr, nullptr, out, bout);
}